// Round 3
// baseline (502.558 us; speedup 1.0000x reference)
//
#include <hip/hip_runtime.h>
#include <cstdint>
#include <cstddef>

typedef __bf16 bf16_t;
typedef __bf16 bf16x8 __attribute__((ext_vector_type(8)));
typedef float  f32x4  __attribute__((ext_vector_type(4)));

#define HEADS    8
#define DIM_HEAD 64
#define SLICE    32
#define DIMC     512      // DIM == INNER == 512
#define BATCH    8
#define NSEQ     8192
#define NTOK     65536

// Async global->LDS, 16B per lane. LDS dest is wave-uniform base + lane*16.
__device__ __forceinline__ void gl2lds16(const bf16_t* g, bf16_t* l) {
  __builtin_amdgcn_global_load_lds(
      (const __attribute__((address_space(1))) uint32_t*)g,
      (__attribute__((address_space(3))) uint32_t*)l, 16, 0, 0);
}

// ---------------------------------------------------------------------------
// x fp32 -> bf16 (xb lives in d_out scratch; dead before GEMM3 writes out)
// ---------------------------------------------------------------------------
__global__ __launch_bounds__(256) void xcast_kernel(const float* __restrict__ x,
                                                    bf16_t* __restrict__ xb) {
  const size_t i = ((size_t)blockIdx.x * 256 + threadIdx.x) * 8;
  const float4 a = *reinterpret_cast<const float4*>(x + i);
  const float4 b = *reinterpret_cast<const float4*>(x + i + 4);
  bf16x8 w;
  w[0] = (bf16_t)a.x; w[1] = (bf16_t)a.y; w[2] = (bf16_t)a.z; w[3] = (bf16_t)a.w;
  w[4] = (bf16_t)b.x; w[5] = (bf16_t)b.y; w[6] = (bf16_t)b.z; w[7] = (bf16_t)b.w;
  *reinterpret_cast<bf16x8*>(xb + i) = w;
}

// ---------------------------------------------------------------------------
// Weight prep: WcT[col][cin] (bf16), per-head column order:
//   col = h*128 + r;  r<32 -> Wq[:,r], r<64 -> Wk[:,r-32], else Wv[:,r-64]
// ---------------------------------------------------------------------------
__global__ __launch_bounds__(256) void wprep_kernel(
    const float* __restrict__ W_in, const float* __restrict__ b_in,
    const float* __restrict__ Wq,   const float* __restrict__ Wk,
    const float* __restrict__ Wv,
    bf16_t* __restrict__ WcT, float* __restrict__ bias_c) {
  __shared__ float sW[8192];                 // Wq[0..2048) Wk[2048..4096) Wv[4096..8192)
  for (int t = threadIdx.x; t < 2048; t += 256) { sW[t] = Wq[t]; sW[2048 + t] = Wk[t]; }
  for (int t = threadIdx.x; t < 4096; t += 256) sW[4096 + t] = Wv[t];
  __syncthreads();

  const int T  = blockIdx.x * 256 + threadIdx.x;
  const int NT = gridDim.x * 256;
  for (int idx = T; idx < 1024 * DIMC; idx += NT) {
    const int col = idx >> 9, cin = idx & 511;
    const int h = col >> 7, r = col & 127;
    int base, ldw, j;
    if (r < 32)      { j = r;      base = 0;    ldw = 32; }
    else if (r < 64) { j = r - 32; base = 2048; ldw = 32; }
    else             { j = r - 64; base = 4096; ldw = 64; }
    const float4* vp = reinterpret_cast<const float4*>(W_in + (size_t)cin * DIMC + h * DIM_HEAD);
    float acc = 0.f;
    #pragma unroll
    for (int d4 = 0; d4 < 16; ++d4) {
      const float4 v = vp[d4];
      acc += v.x * sW[base + (4*d4+0)*ldw + j];
      acc += v.y * sW[base + (4*d4+1)*ldw + j];
      acc += v.z * sW[base + (4*d4+2)*ldw + j];
      acc += v.w * sW[base + (4*d4+3)*ldw + j];
    }
    WcT[(size_t)col * DIMC + cin] = (bf16_t)acc;
  }
  if (T < 1024) {
    const int col = T;
    const int h = col >> 7, r = col & 127;
    int base, ldw, j;
    if (r < 32)      { j = r;      base = 0;    ldw = 32; }
    else if (r < 64) { j = r - 32; base = 2048; ldw = 32; }
    else             { j = r - 64; base = 4096; ldw = 64; }
    const float* vec = b_in + h * DIM_HEAD;
    float acc = 0.f;
    #pragma unroll 8
    for (int d = 0; d < DIM_HEAD; ++d) acc += vec[d] * sW[base + d * ldw + j];
    bias_c[col] = acc;
  }
}

// ---------------------------------------------------------------------------
// 256x256xBK32 MFMA GEMM: 512 threads / 8 waves (2M x 4N), double-buffered
// 64KB STATIC LDS, global_load_lds 16B staging with XOR-chunk swizzle,
// counted vmcnt(2) (never drained mid-loop), raw s_barrier, setprio around
// the two 16-MFMA clusters per tile.
// LDS map (mainloop): A buf b at [b*16K, +16K); B buf b at [32K + b*16K).
// EPI=1 (GEMM1): n-block = 2 heads x [q32|k32|v64]; per-head epilogue phases:
//   q -> softmax (no max-sub; logits tiny) -> bf16 q' [NTOK,256]
//   k -> exp(+bias) -> XOR-swizzled LDS [32][256] + den partial
//   v -> +bias -> XOR-swizzled LDS [64][256]
//   kv[32x64] = ek^T @ v via 8 MFMA/wave; non-atomic per-block f32 partial.
// EPI=0 (GEMM3): fp32 store + bias, batched via blockIdx.z.
// ---------------------------------------------------------------------------
template<int EPI>
__global__ __launch_bounds__(512, 2) void gemm_kernel(
    const bf16_t* __restrict__ A, const bf16_t* __restrict__ Bt,
    void* __restrict__ Cv, const float* __restrict__ bias,
    int K, int lda, int ldc,
    size_t strideA, size_t strideB, size_t strideC,
    float* __restrict__ kvp_g, float* __restrict__ denp_g)
{
  __shared__ char smem[65536];
  const int tid = threadIdx.x;
  // XCD swizzle: same m-slab -> same (p % 8) -> same XCD L2.
  const int p = blockIdx.y * gridDim.x + blockIdx.x;
  int mblk, nblk;
  if (EPI == 1) { mblk = (p & 7) + ((p >> 5) << 3); nblk = (p >> 3) & 3; }
  else          { mblk = (p & 7) + ((p >> 4) << 3); nblk = (p >> 3) & 1; }
  const int m0 = mblk * 256, n0 = nblk * 256;
  const int bz = blockIdx.z;
  const int wave = tid >> 6, lane = tid & 63;
  const int cg = lane & 15, qd = lane >> 4;
  const int wmi = wave >> 2;                 // m-half (0/1)
  const int wm = wmi * 128, wn = (wave & 3) * 64;
  const int srow   = tid >> 2;               // staging row-in-pass (0..127)
  const int gchunk = (tid & 3) ^ ((tid >> 4) & 3);  // XOR column-chunk swizzle

  const bf16_t* Ab = A  + strideA * bz;
  const bf16_t* Bb = Bt + strideB * bz;

  auto stageA = [&](int ko, int buf) {
    #pragma unroll
    for (int p2 = 0; p2 < 2; ++p2)
      gl2lds16(Ab + (size_t)(m0 + p2 * 128 + srow) * lda + ko + gchunk * 8,
               (bf16_t*)(smem + buf * 16384 + p2 * 8192 + tid * 16));
  };
  auto stageB = [&](int ko, int buf) {
    #pragma unroll
    for (int p2 = 0; p2 < 2; ++p2)
      gl2lds16(Bb + (size_t)(n0 + p2 * 128 + srow) * K + ko + gchunk * 8,
               (bf16_t*)(smem + 32768 + buf * 16384 + p2 * 8192 + tid * 16));
  };
  auto ldA = [&](int buf, int r) -> bf16x8 {
    return *(const bf16x8*)(smem + buf * 16384 + r * 64 + ((qd ^ ((r >> 2) & 3)) << 4));
  };
  auto ldB = [&](int buf, int r) -> bf16x8 {
    return *(const bf16x8*)(smem + 32768 + buf * 16384 + r * 64 + ((qd ^ ((r >> 2) & 3)) << 4));
  };

  f32x4 acc[8][4];
  #pragma unroll
  for (int i = 0; i < 8; ++i)
    #pragma unroll
    for (int j = 0; j < 4; ++j) acc[i][j] = (f32x4){0.f, 0.f, 0.f, 0.f};

  // prologue: stage tile 0 into buf 0 (4 loads/thread outstanding)
  stageA(0, 0);
  stageB(0, 0);

  const int T = K >> 5;
  int cur = 0;
  for (int t = 0; t < T; ++t) {
    const int nxt = cur ^ 1;
    const int kn = (t + 1) << 5;
    const bool pf = (t + 1 < T);

    // issue A(t+1), then validate tile t with a counted wait (A(t+1) in flight)
    if (pf) { stageA(kn, nxt); asm volatile("s_waitcnt vmcnt(2)" ::: "memory"); }
    else    { asm volatile("s_waitcnt vmcnt(0)" ::: "memory"); }
    __builtin_amdgcn_s_barrier();

    bf16x8 bF[4], aF[4];
    #pragma unroll
    for (int j = 0; j < 4; ++j) bF[j] = ldB(cur, wn + 16 * j + cg);
    #pragma unroll
    for (int i = 0; i < 4; ++i) aF[i] = ldA(cur, wm + 16 * i + cg);
    __builtin_amdgcn_s_setprio(1);
    #pragma unroll
    for (int i = 0; i < 4; ++i)
      #pragma unroll
      for (int j = 0; j < 4; ++j)
        acc[i][j] = __builtin_amdgcn_mfma_f32_16x16x32_bf16(aF[i], bF[j], acc[i][j], 0, 0, 0);
    __builtin_amdgcn_s_setprio(0);

    if (pf) stageB(kn, nxt);
    bf16x8 aG[4];
    #pragma unroll
    for (int i = 0; i < 4; ++i) aG[i] = ldA(cur, wm + 64 + 16 * i + cg);
    __builtin_amdgcn_s_setprio(1);
    #pragma unroll
    for (int i = 0; i < 4; ++i)
      #pragma unroll
      for (int j = 0; j < 4; ++j)
        acc[i + 4][j] = __builtin_amdgcn_mfma_f32_16x16x32_bf16(aG[i], bF[j], acc[i + 4][j], 0, 0, 0);
    __builtin_amdgcn_s_setprio(0);
    __builtin_amdgcn_s_barrier();   // all reads of buf cur done before it is restaged
    cur = nxt;
  }

  if (EPI == 1) {
    __syncthreads();                           // full fence before LDS reuse
    const int role = wave & 3;                 // 0/2: q+k (head 0/1), 1/3: v
    const int bat = mblk >> 5, mb = mblk & 31; // 32 m-blocks per batch
    char*  ekT   = smem;                       // [32 s][512B], XOR-swizzled
    char*  vT    = smem + 32768;               // [64 c][512B], XOR-swizzled
    float* den_s = (float*)(smem + 16384);     // [2 wmi][32 s]

    for (int h = 0; h < 2; ++h) {
      if (role == 2 * h) {
        // ---- q softmax over this head's 32 q cols (j=0,1); logits tiny ----
        const float bq0 = bias[n0 + h * 128 + cg];
        const float bq1 = bias[n0 + h * 128 + 16 + cg];
        #pragma unroll
        for (int i = 0; i < 8; ++i) {
          #pragma unroll
          for (int rr = 0; rr < 4; ++rr) {
            const float e0 = __expf(acc[i][0][rr] + bq0);
            const float e1 = __expf(acc[i][1][rr] + bq1);
            float s = e0 + e1;
            #pragma unroll
            for (int d = 1; d < 16; d <<= 1) s += __shfl_xor(s, d, 64);
            const float rs = 1.f / s;
            const int row = m0 + wm + 16 * i + qd * 4 + rr;
            bf16_t* crow = (bf16_t*)Cv + (size_t)row * ldc + (nblk * 2 + h) * SLICE;
            crow[cg]      = (bf16_t)(e0 * rs);
            crow[16 + cg] = (bf16_t)(e1 * rs);
          }
        }
        // ---- ek = exp(k + bias) (j=2,3) -> swizzled LDS + den partial ----
        #pragma unroll
        for (int j = 2; j < 4; ++j) {
          const int s_i = 16 * (j - 2) + cg;
          const float bk = bias[n0 + h * 128 + 32 + 16 * (j - 2) + cg];
          float dsum = 0.f;
          #pragma unroll
          for (int i = 0; i < 8; ++i) {
            #pragma unroll
            for (int rr = 0; rr < 4; ++rr) {
              const float e = __expf(acc[i][j][rr] + bk);
              dsum += e;
              const int n = wm + 16 * i + qd * 4 + rr;
              *(bf16_t*)(ekT + (s_i << 9) + ((2 * n) ^ ((s_i & 7) << 4))) = (bf16_t)e;
            }
          }
          dsum += __shfl_xor(dsum, 16, 64);
          dsum += __shfl_xor(dsum, 32, 64);
          if (qd == 0) den_s[wmi * 32 + s_i] = dsum;
        }
      } else if (role == 2 * h + 1) {
        // ---- v + bias -> swizzled LDS (64 cols) ----
        #pragma unroll
        for (int j = 0; j < 4; ++j) {
          const int c = 16 * j + cg;
          const float bv = bias[n0 + h * 128 + 64 + c];
          #pragma unroll
          for (int i = 0; i < 8; ++i) {
            #pragma unroll
            for (int rr = 0; rr < 4; ++rr) {
              const float vv = acc[i][j][rr] + bv;
              const int n = wm + 16 * i + qd * 4 + rr;
              *(bf16_t*)(vT + (c << 9) + ((2 * n) ^ ((c & 7) << 4))) = (bf16_t)vv;
            }
          }
        }
      }
      __syncthreads();
      const int bh = bat * HEADS + nblk * 2 + h;
      if (tid < SLICE)
        denp_g[((size_t)bh * 32 + mb) * SLICE + tid] = den_s[tid] + den_s[32 + tid];
      // ---- kv outer product: kv[s][c] = sum_{n<256} ek[n,s]*v[n,c] ----
      // 8 tiles of 16x16 (2 s-tiles x 4 c-tiles), one per wave, K=256.
      const int st = wave & 1, ct = wave >> 1;
      const int sA = st * 16 + cg;
      const int cB = ct * 16 + cg;
      f32x4 kacc = (f32x4){0.f, 0.f, 0.f, 0.f};
      #pragma unroll
      for (int kk = 0; kk < 8; ++kk) {
        const bf16x8 afr = *(const bf16x8*)(ekT + (sA << 9) + ((kk * 64 + qd * 16) ^ ((sA & 7) << 4)));
        const bf16x8 bfr = *(const bf16x8*)(vT  + (cB << 9) + ((kk * 64 + qd * 16) ^ ((cB & 7) << 4)));
        kacc = __builtin_amdgcn_mfma_f32_16x16x32_bf16(afr, bfr, kacc, 0, 0, 0);
      }
      float* kvp = kvp_g + ((size_t)bh * 32 + mb) * 2048;
      #pragma unroll
      for (int r = 0; r < 4; ++r)
        kvp[(st * 16 + qd * 4 + r) * 64 + cB] = kacc[r];
      __syncthreads();   // ek/v consumed before next head overwrites
    }
  } else {
    #pragma unroll
    for (int j = 0; j < 4; ++j) {
      const int col = n0 + wn + 16 * j + cg;
      const float bv = bias[col];
      #pragma unroll
      for (int i = 0; i < 8; ++i) {
        #pragma unroll
        for (int rr = 0; rr < 4; ++rr) {
          const int row = m0 + wm + 16 * i + qd * 4 + rr;
          ((float*)Cv + strideC * bz)[(size_t)row * ldc + col] = acc[i][j][rr] + bv;
        }
      }
    }
  }
}

// ---------------------------------------------------------------------------
// kv partial reduction: kv_red[bh][2048] = sum_mb kv_part[bh][mb][2048]
// ---------------------------------------------------------------------------
__global__ __launch_bounds__(256) void kvreduce_kernel(const float* __restrict__ kv_part,
                                                       const float* __restrict__ den_part,
                                                       float* __restrict__ kv_red,
                                                       float* __restrict__ den_red) {
  const int ch = blockIdx.x, bh = blockIdx.y;
  const int tid = threadIdx.x;
  const float* src = kv_part + (size_t)bh * 32 * 2048 + ch * 256 + tid;
  float s = 0.f;
  #pragma unroll
  for (int mb = 0; mb < 32; ++mb) s += src[(size_t)mb * 2048];
  kv_red[(size_t)bh * 2048 + ch * 256 + tid] = s;
  if (ch == 0 && tid < 32) {
    const float* dsrc = den_part + (size_t)bh * 32 * 32 + tid;
    float d = 0.f;
    #pragma unroll
    for (int mb = 0; mb < 32; ++mb) d += dsrc[mb * 32];
    den_red[bh * 32 + tid] = d;
  }
}

// ---------------------------------------------------------------------------
// M prep: normalize kv, then Mt[b][outc][h*32+s] = sum_c kvn[s][c]*W_out[h*64+c][outc]
// ---------------------------------------------------------------------------
__global__ __launch_bounds__(512) void mprep_kernel(const float* __restrict__ kv_red,
                                                    const float* __restrict__ den_red,
                                                    const float* __restrict__ W_out,
                                                    bf16_t* __restrict__ Mt) {
  const int bh = blockIdx.x, bat = bh >> 3, h = bh & 7;
  const int tid = threadIdx.x;
  __shared__ float kvn[SLICE][DIM_HEAD];   // 8 KB (normalized kv)
  __shared__ float wbuf[8][DIMC];          // 16 KB
  const float* src = kv_red + (size_t)bh * 2048;
  const float* dp  = den_red + bh * 32;
  for (int t = tid; t < 2048; t += 512) kvn[t >> 6][t & 63] = src[t] / dp[t >> 6];

  float accs[SLICE];
  #pragma unroll
  for (int s = 0; s < SLICE; ++s) accs[s] = 0.f;
  for (int cb = 0; cb < DIM_HEAD; cb += 8) {
    __syncthreads();
    for (int t = tid; t < 8 * DIMC; t += 512)
      wbuf[t >> 9][t & 511] = W_out[(size_t)(h * DIM_HEAD + cb + (t >> 9)) * DIMC + (t & 511)];
    __syncthreads();
    #pragma unroll
    for (int cc = 0; cc < 8; ++cc) {
      const float wv = wbuf[cc][tid];
      #pragma unroll
      for (int s = 0; s < SLICE; ++s) accs[s] += kvn[s][cb + cc] * wv;
    }
  }
  bf16_t* dst = Mt + (size_t)bat * (DIMC * 256) + (size_t)tid * 256 + h * SLICE;
  #pragma unroll
  for (int s = 0; s < SLICE; ++s) dst[s] = (bf16_t)accs[s];
}

// ---------------------------------------------------------------------------
extern "C" void kernel_launch(void* const* d_in, const int* in_sizes, int n_in,
                              void* d_out, int out_size, void* d_ws, size_t ws_size,
                              hipStream_t stream) {
  const float* x     = (const float*)d_in[0];
  const float* W_in  = (const float*)d_in[1];
  const float* b_in  = (const float*)d_in[2];
  const float* Wq    = (const float*)d_in[3];
  const float* Wk    = (const float*)d_in[4];
  const float* Wv    = (const float*)d_in[5];
  const float* W_out = (const float*)d_in[6];
  const float* b_out = (const float*)d_in[7];

  uint8_t* ws = (uint8_t*)d_ws;
  bf16_t* qprime   = (bf16_t*)(ws);                     // 65536*256 bf16 = 33554432 B
  bf16_t* WcT      = (bf16_t*)(ws + 33554432ull);       // 1024*512 bf16  = 1048576 B
  float*  bias_c   = (float*) (ws + 34603008ull);       // 1024 f32       = 4096 B
  float*  kv_part  = (float*) (ws + 34607104ull);       // 64*32*2048 f32 = 16777216 B
  float*  den_part = (float*) (ws + 51384320ull);       // 64*32*32 f32   = 262144 B
  float*  kv_red   = (float*) (ws + 51646464ull);       // 64*2048 f32    = 524288 B
  float*  den_red  = (float*) (ws + 52170752ull);       // 64*32 f32      = 8192 B
  bf16_t* Mt       = (bf16_t*)(ws + 52178944ull);       // 8*512*256 bf16 = 2097152 B
  // x_bf16 scratch lives in d_out (134 MB): dead before GEMM3 writes out.
  bf16_t* xb = (bf16_t*)d_out;                          // 65536*512 bf16 = 67108864 B

  xcast_kernel<<<dim3(NTOK * DIMC / 8 / 256), dim3(256), 0, stream>>>(x, xb);
  wprep_kernel<<<dim3(256), dim3(256), 0, stream>>>(W_in, b_in, Wq, Wk, Wv, WcT, bias_c);

  // GEMM1: xb [65536,512] @ WcT -> q' [65536,256] bf16 + kv/den partials
  gemm_kernel<1><<<dim3(8, 128, 1), dim3(512), 0, stream>>>(
      xb, WcT, (void*)qprime, bias_c,
      512 /*K*/, 512 /*lda*/, 256 /*ldc*/, (size_t)0, (size_t)0, (size_t)0,
      kv_part, den_part);

  kvreduce_kernel<<<dim3(8, 64), dim3(256), 0, stream>>>(kv_part, den_part, kv_red, den_red);
  mprep_kernel<<<dim3(BATCH * HEADS), dim3(512), 0, stream>>>(kv_red, den_red, W_out, Mt);

  // GEMM3 (batched over b): q' [8192,256] bf16 @ Mt[b] -> out [8192,512] f32
  gemm_kernel<0><<<dim3(8, 8, BATCH), dim3(512), 0, stream>>>(
      qprime, Mt, d_out, b_out,
      256 /*K*/, 256 /*lda*/, DIMC /*ldc*/,
      (size_t)NSEQ * 256, (size_t)DIMC * 256, (size_t)NSEQ * DIMC,
      nullptr, nullptr);
}